// Round 4
// baseline (219.785 us; speedup 1.0000x reference)
//
#include <hip/hip_runtime.h>
#include <hip/hip_bf16.h>

#define BATCH   65536
#define FEAT    128
#define KDIM    256

typedef __attribute__((ext_vector_type(8))) short bf16x8;
typedef __attribute__((ext_vector_type(4))) float f32x4;

__device__ __forceinline__ short f2bf(float f) {
    return __builtin_bit_cast(short, __float2bfloat16(f));
}

__device__ __forceinline__ bf16x8 cvt8(f32x4 lo, f32x4 hi) {
    bf16x8 r;
    r[0] = f2bf(lo[0]); r[1] = f2bf(lo[1]); r[2] = f2bf(lo[2]); r[3] = f2bf(lo[3]);
    r[4] = f2bf(hi[0]); r[5] = f2bf(hi[1]); r[6] = f2bf(hi[2]); r[7] = f2bf(hi[3]);
    return r;
}

// pack two fp32 partials as bf16 pair in one u32 (low = a, high = b)
__device__ __forceinline__ unsigned int pk2(float a, float b) {
    unsigned short ua = __builtin_bit_cast(unsigned short, __float2bfloat16(a));
    unsigned short ub = __builtin_bit_cast(unsigned short, __float2bfloat16(b));
    return (unsigned int)ua | ((unsigned int)ub << 16);
}
__device__ __forceinline__ float bflo(unsigned int p) {
    return __builtin_bit_cast(float, p << 16);
}
__device__ __forceinline__ float bfhi(unsigned int p) {
    return __builtin_bit_cast(float, p & 0xffff0000u);
}

__device__ __forceinline__ float sigmoidf_(float x) {
    return 1.0f / (1.0f + __expf(-x));
}
__device__ __forceinline__ float tanhf_(float x) {
    float xc = fminf(fmaxf(x, -15.0f), 15.0f);
    float e = __expf(-2.0f * xc);
    return (1.0f - e) / (1.0f + e);
}

// K-split across 4 waves (wave = K-quarter), persistent 1024 blocks (4/CU).
// Software-pipelined: A(it+1) issued right after the MFMA phase consumes the
// staging regs (flies across barrier+epilogue); cel(it+1) issued at epilogue
// end. Partials exchanged as packed bf16 pairs through a DOUBLE-BUFFERED LDS
// (one barrier per iteration instead of two).
__global__ __launch_bounds__(256, 4)
void lstm_v3(const float* __restrict__ inp, const float* __restrict__ hid,
             const float* __restrict__ cel,
             const float* __restrict__ Wf, const float* __restrict__ bfp,
             const float* __restrict__ Wi, const float* __restrict__ bip,
             const float* __restrict__ Wo, const float* __restrict__ bop,
             const float* __restrict__ Wc, const float* __restrict__ bcp,
             float* __restrict__ out)
{
    // [dbuf][kq][lane][17 u32]; stride 17 -> write bank 17*lane%32 bijective
    // over 32, 2-way over 64 lanes (free); 34816 B -> 4 blocks/CU.
    __shared__ unsigned int plds[2][4][64][17];

    const int tid  = threadIdx.x;
    const int lane = tid & 63;
    const int wid  = tid >> 6;          // = kq, this wave's K-quarter
    const int bid  = blockIdx.x;
    const int cg   = bid >> 7;          // 0..7 column group
    const int rtg  = bid & 127;         // 0..127 row-tile group (same XCD for all cg)

    const int lr = lane & 15;
    const int lk = lane >> 4;
    const int j  = cg * 16 + lr;        // hidden-unit column

    const int kq = wid;
    const int k0 = (kq & 1) * 64;
    const float* Asrc = (kq < 2) ? inp : hid;

    // ---- W fragments for this K-quarter: 32 VGPRs ----
    bf16x8 w[4][2];
    {
        const float* wsrc[4] = {Wf, Wi, Wo, Wc};
        #pragma unroll
        for (int g = 0; g < 4; ++g) {
            const float* s = wsrc[g] + (size_t)j * KDIM + kq * 64 + lk * 8;
            #pragma unroll
            for (int ks = 0; ks < 2; ++ks) {
                f32x4 lo = *(const f32x4*)(s + ks * 32);
                f32x4 hi = *(const f32x4*)(s + ks * 32 + 4);
                w[g][ks] = cvt8(lo, hi);
            }
        }
    }
    const float bsf = bfp[j], bsi = bip[j], bso = bop[j], bsc = bcp[j];

    float* outH = out;
    float* outC = out + (size_t)BATCH * FEAT;

    // ---- prologue: A(0) and cel(0) in flight ----
    f32x4 alo[2][2], ahi[2][2];     // [ks][mb] staging, reused as prefetch buf
    {
        const float* a = Asrc + (size_t)((rtg * 32) + lr) * FEAT + k0 + lk * 8;
        #pragma unroll
        for (int ks = 0; ks < 2; ++ks)
            #pragma unroll
            for (int mb = 0; mb < 2; ++mb) {
                alo[ks][mb] = *(const f32x4*)(a + mb * 16 * FEAT + ks * 32);
                ahi[ks][mb] = *(const f32x4*)(a + mb * 16 * FEAT + ks * 32 + 4);
            }
    }
    float cv[2];
    #pragma unroll
    for (int p = 0; p < 2; ++p) {
        const int rl = wid * 8 + p * 4 + lk;
        cv[p] = cel[(size_t)(rtg * 32 + rl) * FEAT + j];
    }

    for (int it = 0; it < 16; ++it) {
        const int R0 = (rtg + it * 128) * 32;

        // ---- MFMA phase ----
        f32x4 acc[2][4];
        #pragma unroll
        for (int mb = 0; mb < 2; ++mb)
            #pragma unroll
            for (int g = 0; g < 4; ++g)
                acc[mb][g] = (f32x4){0.f, 0.f, 0.f, 0.f};

        #pragma unroll
        for (int ks = 0; ks < 2; ++ks) {
            bf16x8 a0 = cvt8(alo[ks][0], ahi[ks][0]);
            bf16x8 a1 = cvt8(alo[ks][1], ahi[ks][1]);
            #pragma unroll
            for (int g = 0; g < 4; ++g) {
                acc[0][g] = __builtin_amdgcn_mfma_f32_16x16x32_bf16(a0, w[g][ks], acc[0][g], 0, 0, 0);
                acc[1][g] = __builtin_amdgcn_mfma_f32_16x16x32_bf16(a1, w[g][ks], acc[1][g], 0, 0, 0);
            }
        }

        // ---- prefetch A(it+1): staging regs are dead after cvt above ----
        if (it < 15) {
            const int R0n = (rtg + (it + 1) * 128) * 32;
            const float* an = Asrc + (size_t)(R0n + lr) * FEAT + k0 + lk * 8;
            #pragma unroll
            for (int ks = 0; ks < 2; ++ks)
                #pragma unroll
                for (int mb = 0; mb < 2; ++mb) {
                    alo[ks][mb] = *(const f32x4*)(an + mb * 16 * FEAT + ks * 32);
                    ahi[ks][mb] = *(const f32x4*)(an + mb * 16 * FEAT + ks * 32 + 4);
                }
        }

        // ---- pack partials (bf16 pairs) and write this wave's slice ----
        {
            unsigned int* dst = &plds[it & 1][kq][lane][0];
            #pragma unroll
            for (int mb = 0; mb < 2; ++mb)
                #pragma unroll
                for (int t = 0; t < 4; ++t) {
                    dst[mb * 8 + t * 2 + 0] = pk2(acc[mb][0][t], acc[mb][1][t]);
                    dst[mb * 8 + t * 2 + 1] = pk2(acc[mb][2][t], acc[mb][3][t]);
                }
        }
        __syncthreads();   // single barrier: dbuf makes write(t+1) safe vs read(t)

        // ---- cross-wave reduce + LSTM epilogue; this wave owns 8 rows ----
        #pragma unroll
        for (int p = 0; p < 2; ++p) {
            const int rl  = wid * 8 + p * 4 + lk;    // 0..31 (mb,lk2 wave-uniform)
            const int jc  = lr;
            const int mb  = rl >> 4;
            const int lk2 = (rl >> 2) & 3;
            const int t   = rl & 3;
            const int sl  = lk2 * 16 + jc;           // producer lane

            float s0 = 0.f, s1 = 0.f, s2 = 0.f, s3 = 0.f;
            #pragma unroll
            for (int q = 0; q < 4; ++q) {
                unsigned int pA = plds[it & 1][q][sl][mb * 8 + t * 2 + 0];
                unsigned int pB = plds[it & 1][q][sl][mb * 8 + t * 2 + 1];
                s0 += bflo(pA); s1 += bfhi(pA);
                s2 += bflo(pB); s3 += bfhi(pB);
            }

            const size_t off = (size_t)(R0 + rl) * FEAT + j;
            float fg = sigmoidf_(s0 + bsf);
            float ig = sigmoidf_(s1 + bsi);
            float og = sigmoidf_(s2 + bso);
            float gg = tanhf_(s3 + bsc);
            float nc = fg * cv[p] + ig * gg;
            float nh = og * tanhf_(nc);
            outH[off] = nh;
            outC[off] = nc;
        }

        // ---- prefetch cel(it+1) after last use of cv ----
        if (it < 15) {
            const int R0n = (rtg + (it + 1) * 128) * 32;
            #pragma unroll
            for (int p = 0; p < 2; ++p) {
                const int rl = wid * 8 + p * 4 + lk;
                cv[p] = cel[(size_t)(R0n + rl) * FEAT + j];
            }
        }
    }
}

extern "C" void kernel_launch(void* const* d_in, const int* in_sizes, int n_in,
                              void* d_out, int out_size, void* d_ws, size_t ws_size,
                              hipStream_t stream) {
    const float* inp = (const float*)d_in[0];
    const float* hid = (const float*)d_in[1];
    const float* cel = (const float*)d_in[2];
    const float* Wf  = (const float*)d_in[3];
    const float* bf  = (const float*)d_in[4];
    const float* Wi  = (const float*)d_in[5];
    const float* bi  = (const float*)d_in[6];
    const float* Wo  = (const float*)d_in[7];
    const float* bo  = (const float*)d_in[8];
    const float* Wc  = (const float*)d_in[9];
    const float* bc  = (const float*)d_in[10];
    float* out = (float*)d_out;

    lstm_v3<<<dim3(1024), dim3(256), 0, stream>>>(
        inp, hid, cel, Wf, bf, Wi, bi, Wo, bo, Wc, bc, out);
}

// Round 7
// 215.750 us; speedup vs baseline: 1.0187x; 1.0187x over previous
//
#include <hip/hip_runtime.h>
#include <hip/hip_bf16.h>

#define BATCH   65536
#define FEAT    128
#define KDIM    256

typedef __attribute__((ext_vector_type(8))) short bf16x8;
typedef __attribute__((ext_vector_type(4))) float f32x4;

__device__ __forceinline__ short f2bf(float f) {
    return __builtin_bit_cast(short, __float2bfloat16(f));
}

__device__ __forceinline__ bf16x8 cvt8(f32x4 lo, f32x4 hi) {
    bf16x8 r;
    r[0] = f2bf(lo[0]); r[1] = f2bf(lo[1]); r[2] = f2bf(lo[2]); r[3] = f2bf(lo[3]);
    r[4] = f2bf(hi[0]); r[5] = f2bf(hi[1]); r[6] = f2bf(hi[2]); r[7] = f2bf(hi[3]);
    return r;
}

// pack two fp32 partials as bf16 pair in one u32 (low = a, high = b)
__device__ __forceinline__ unsigned int pk2(float a, float b) {
    unsigned short ua = __builtin_bit_cast(unsigned short, __float2bfloat16(a));
    unsigned short ub = __builtin_bit_cast(unsigned short, __float2bfloat16(b));
    return (unsigned int)ua | ((unsigned int)ub << 16);
}
__device__ __forceinline__ float bflo(unsigned int p) {
    return __builtin_bit_cast(float, p << 16);
}
__device__ __forceinline__ float bfhi(unsigned int p) {
    return __builtin_bit_cast(float, p & 0xffff0000u);
}

__device__ __forceinline__ float sigmoidf_(float x) {
    return 1.0f / (1.0f + __expf(-x));
}
__device__ __forceinline__ float tanhf_(float x) {
    float xc = fminf(fmaxf(x, -15.0f), 15.0f);
    float e = __expf(-2.0f * xc);
    return (1.0f - e) / (1.0f + e);
}

// K-split across 4 waves (wave = K-quarter), persistent 1024 blocks (4/CU).
// Identical to the passing v3 EXCEPT the barrier: raw s_barrier with
// producer-side lgkmcnt(0) instead of __syncthreads(), so the A(it+1) and
// cel(it+1) global prefetches are NOT drained at the barrier (T4: counted
// vmcnt across barriers). LDS safety: ds_writes are lgkm-complete before
// barrier arrival; ds_reads of buf[t] are consumed (compiler lgkm waits)
// before the next barrier, so writes to buf[t] at iteration t+2 cannot race.
__global__ __launch_bounds__(256, 4)
void lstm_v5(const float* __restrict__ inp, const float* __restrict__ hid,
             const float* __restrict__ cel,
             const float* __restrict__ Wf, const float* __restrict__ bfp,
             const float* __restrict__ Wi, const float* __restrict__ bip,
             const float* __restrict__ Wo, const float* __restrict__ bop,
             const float* __restrict__ Wc, const float* __restrict__ bcp,
             float* __restrict__ out)
{
    // [dbuf][kq][lane][17 u32]; stride 17 -> write bank 17*lane%32 bijective
    // over 32, 2-way over 64 lanes (free); 34816 B -> 4 blocks/CU.
    __shared__ unsigned int plds[2][4][64][17];

    const int tid  = threadIdx.x;
    const int lane = tid & 63;
    const int wid  = tid >> 6;          // = kq, this wave's K-quarter
    const int bid  = blockIdx.x;
    const int cg   = bid >> 7;          // 0..7 column group
    const int rtg  = bid & 127;         // 0..127 row-tile group; bid%8 = rtg%8
                                        // -> all 8 cg-blocks of a row-tile on
                                        // the same XCD's L2 (A-reuse)

    const int lr = lane & 15;
    const int lk = lane >> 4;
    const int j  = cg * 16 + lr;        // hidden-unit column

    const int kq = wid;
    const int k0 = (kq & 1) * 64;
    const float* Asrc = (kq < 2) ? inp : hid;

    // ---- W fragments for this K-quarter: 32 VGPRs ----
    bf16x8 w[4][2];
    {
        const float* wsrc[4] = {Wf, Wi, Wo, Wc};
        #pragma unroll
        for (int g = 0; g < 4; ++g) {
            const float* s = wsrc[g] + (size_t)j * KDIM + kq * 64 + lk * 8;
            #pragma unroll
            for (int ks = 0; ks < 2; ++ks) {
                f32x4 lo = *(const f32x4*)(s + ks * 32);
                f32x4 hi = *(const f32x4*)(s + ks * 32 + 4);
                w[g][ks] = cvt8(lo, hi);
            }
        }
    }
    const float bsf = bfp[j], bsi = bip[j], bso = bop[j], bsc = bcp[j];

    float* outH = out;
    float* outC = out + (size_t)BATCH * FEAT;

    // ---- prologue: A(0) and cel(0) in flight ----
    f32x4 alo[2][2], ahi[2][2];     // [ks][mb] staging, reused as prefetch buf
    {
        const float* a = Asrc + (size_t)((rtg * 32) + lr) * FEAT + k0 + lk * 8;
        #pragma unroll
        for (int ks = 0; ks < 2; ++ks)
            #pragma unroll
            for (int mb = 0; mb < 2; ++mb) {
                alo[ks][mb] = *(const f32x4*)(a + mb * 16 * FEAT + ks * 32);
                ahi[ks][mb] = *(const f32x4*)(a + mb * 16 * FEAT + ks * 32 + 4);
            }
    }
    float cv[2];
    #pragma unroll
    for (int p = 0; p < 2; ++p) {
        const int rl = wid * 8 + p * 4 + lk;
        cv[p] = cel[(size_t)(rtg * 32 + rl) * FEAT + j];
    }

    for (int it = 0; it < 16; ++it) {
        const int R0 = (rtg + it * 128) * 32;

        // ---- MFMA phase ----
        f32x4 acc[2][4];
        #pragma unroll
        for (int mb = 0; mb < 2; ++mb)
            #pragma unroll
            for (int g = 0; g < 4; ++g)
                acc[mb][g] = (f32x4){0.f, 0.f, 0.f, 0.f};

        #pragma unroll
        for (int ks = 0; ks < 2; ++ks) {
            bf16x8 a0 = cvt8(alo[ks][0], ahi[ks][0]);
            bf16x8 a1 = cvt8(alo[ks][1], ahi[ks][1]);
            #pragma unroll
            for (int g = 0; g < 4; ++g) {
                acc[0][g] = __builtin_amdgcn_mfma_f32_16x16x32_bf16(a0, w[g][ks], acc[0][g], 0, 0, 0);
                acc[1][g] = __builtin_amdgcn_mfma_f32_16x16x32_bf16(a1, w[g][ks], acc[1][g], 0, 0, 0);
            }
        }

        // ---- prefetch A(it+1): staging regs are dead after cvt above.
        // These loads stay IN FLIGHT across the raw barrier below (no vmcnt
        // drain) and are waited with counted vmcnt at next iter's cvt.
        if (it < 15) {
            const int R0n = (rtg + (it + 1) * 128) * 32;
            const float* an = Asrc + (size_t)(R0n + lr) * FEAT + k0 + lk * 8;
            #pragma unroll
            for (int ks = 0; ks < 2; ++ks)
                #pragma unroll
                for (int mb = 0; mb < 2; ++mb) {
                    alo[ks][mb] = *(const f32x4*)(an + mb * 16 * FEAT + ks * 32);
                    ahi[ks][mb] = *(const f32x4*)(an + mb * 16 * FEAT + ks * 32 + 4);
                }
        }

        // ---- pack partials (bf16 pairs) and write this wave's slice ----
        {
            unsigned int* dst = &plds[it & 1][kq][lane][0];
            #pragma unroll
            for (int mb = 0; mb < 2; ++mb)
                #pragma unroll
                for (int t = 0; t < 4; ++t) {
                    dst[mb * 8 + t * 2 + 0] = pk2(acc[mb][0][t], acc[mb][1][t]);
                    dst[mb * 8 + t * 2 + 1] = pk2(acc[mb][2][t], acc[mb][3][t]);
                }
        }

        // ---- raw barrier: drain LDS writes only, NOT the global prefetch ----
        asm volatile("s_waitcnt lgkmcnt(0)" ::: "memory");
        __builtin_amdgcn_s_barrier();
        asm volatile("" ::: "memory");

        // ---- cross-wave reduce + LSTM epilogue; this wave owns 8 rows ----
        #pragma unroll
        for (int p = 0; p < 2; ++p) {
            const int rl  = wid * 8 + p * 4 + lk;    // 0..31
            const int jc  = lr;
            const int mb  = rl >> 4;
            const int lk2 = (rl >> 2) & 3;
            const int t   = rl & 3;
            const int sl  = lk2 * 16 + jc;           // producer lane

            float s0 = 0.f, s1 = 0.f, s2 = 0.f, s3 = 0.f;
            #pragma unroll
            for (int q = 0; q < 4; ++q) {
                unsigned int pA = plds[it & 1][q][sl][mb * 8 + t * 2 + 0];
                unsigned int pB = plds[it & 1][q][sl][mb * 8 + t * 2 + 1];
                s0 += bflo(pA); s1 += bfhi(pA);
                s2 += bflo(pB); s3 += bfhi(pB);
            }

            const size_t off = (size_t)(R0 + rl) * FEAT + j;
            float fg = sigmoidf_(s0 + bsf);
            float ig = sigmoidf_(s1 + bsi);
            float og = sigmoidf_(s2 + bso);
            float gg = tanhf_(s3 + bsc);
            float nc = fg * cv[p] + ig * gg;
            float nh = og * tanhf_(nc);
            outH[off] = nh;
            outC[off] = nc;
        }

        // ---- prefetch cel(it+1) after last use of cv ----
        if (it < 15) {
            const int R0n = (rtg + (it + 1) * 128) * 32;
            #pragma unroll
            for (int p = 0; p < 2; ++p) {
                const int rl = wid * 8 + p * 4 + lk;
                cv[p] = cel[(size_t)(R0n + rl) * FEAT + j];
            }
        }
    }
}

extern "C" void kernel_launch(void* const* d_in, const int* in_sizes, int n_in,
                              void* d_out, int out_size, void* d_ws, size_t ws_size,
                              hipStream_t stream) {
    const float* inp = (const float*)d_in[0];
    const float* hid = (const float*)d_in[1];
    const float* cel = (const float*)d_in[2];
    const float* Wf  = (const float*)d_in[3];
    const float* bf  = (const float*)d_in[4];
    const float* Wi  = (const float*)d_in[5];
    const float* bi  = (const float*)d_in[6];
    const float* Wo  = (const float*)d_in[7];
    const float* bo  = (const float*)d_in[8];
    const float* Wc  = (const float*)d_in[9];
    const float* bc  = (const float*)d_in[10];
    float* out = (float*)d_out;

    lstm_v5<<<dim3(1024), dim3(256), 0, stream>>>(
        inp, hid, cel, Wf, bf, Wi, bi, Wo, bo, Wc, bc, out);
}